// Round 3
// baseline (425.972 us; speedup 1.0000x reference)
//
#include <hip/hip_runtime.h>
#include <hip/hip_bf16.h>

#define B_   512
#define V_   6890
#define NJ_  24
#define NB_  10
#define NP_  207
#define NJO_ 19
#define K_   224          // 10 beta + 207 pose_feature + 7 zero pad
#define N3V  20670        // V_*3

typedef __attribute__((ext_vector_type(8))) short short8;   // 8 bf16 (4 VGPRs)
typedef __attribute__((ext_vector_type(4))) float f32x4;    // 4 fp32 acc

// ---------------- ws layout (floats) ----------------  total 205592 fl = 822 KB
// PF   : bf16 [512][224]          @ 0        (57344 floats)
// Abuf : fp32 [512][24*12]        @ 57344    (147456 floats)
// srtr : SR[10][24][3]+TR[24][3]  @ 204800   (792 floats)

// ---------------- d_out layout (floats) -------------
// vertices @ 0          (512*6890*3 = 10583040)
// joints   @ 10583040   (512*19*3   = 29184)
// rot      @ 10612224   (512*24*9   = 110592)

__device__ __forceinline__ unsigned short f2bf(float x) {
  __hip_bfloat16 h = __float2bfloat16(x);
  return *(unsigned short*)&h;
}

// K_sr: SR[k,j,c] = sum_v shapes[k,3v+c]*sreg[v,j];  TR[j,c] = sum_v vt[v,c]*sreg[v,j]
__global__ void __launch_bounds__(256) k_sr(const float* __restrict__ shapes,
                                            const float* __restrict__ vt,
                                            const float* __restrict__ sreg,
                                            float* __restrict__ srtr) {
  int j = blockIdx.x;          // 24 blocks
  int tid = threadIdx.x;
  float acc[33];
#pragma unroll
  for (int a = 0; a < 33; a++) acc[a] = 0.f;
  for (int v = tid; v < V_; v += 256) {
    float w = sreg[v * NJ_ + j];
#pragma unroll
    for (int k = 0; k < NB_; k++) {
      const float* sp = shapes + k * N3V + 3 * v;
#pragma unroll
      for (int c = 0; c < 3; c++) acc[k * 3 + c] += w * sp[c];
    }
#pragma unroll
    for (int c = 0; c < 3; c++) acc[30 + c] += w * vt[3 * v + c];
  }
  __shared__ float red[4][33];
  int wave = tid >> 6, lane = tid & 63;
#pragma unroll
  for (int a = 0; a < 33; a++) {
    float x = acc[a];
#pragma unroll
    for (int m = 1; m < 64; m <<= 1) x += __shfl_xor(x, m, 64);
    if (lane == 0) red[wave][a] = x;
  }
  __syncthreads();
  if (tid < 33) {
    float s = red[0][tid] + red[1][tid] + red[2][tid] + red[3][tid];
    if (tid < 30) srtr[((tid / 3) * NJ_ + j) * 3 + (tid % 3)] = s;
    else          srtr[720 + j * 3 + (tid - 30)] = s;
  }
}

// K_rodpf: rodrigues per (b,j); writes rot output + bf16 PF rows [beta | pose_feat | 0-pad]
__global__ void __launch_bounds__(256) k_rodpf(const float* __restrict__ in,
                                               float* __restrict__ out_rot,
                                               unsigned short* __restrict__ PF) {
  int idx = blockIdx.x * 256 + threadIdx.x;   // 48 blocks * 256 = 12288
  int b = idx & (B_ - 1);
  int j = idx >> 9;
  const float* r = in + b * 82 + j * 3;
  float r0 = r[0], r1 = r[1], r2 = r[2];
  float ax = r0 + 1e-8f, ay = r1 + 1e-8f, az = r2 + 1e-8f;
  float angle = sqrtf(ax * ax + ay * ay + az * az);
  float inv = 1.0f / angle;
  float n0 = r0 * inv, n1 = r1 * inv, n2 = r2 * inv;
  float c = cosf(angle), s = sinf(angle);
  float ic = 1.0f - c;
  float R[9];
  R[0] = c + ic * n0 * n0;      R[1] = ic * n0 * n1 - s * n2;  R[2] = ic * n0 * n2 + s * n1;
  R[3] = ic * n1 * n0 + s * n2; R[4] = c + ic * n1 * n1;       R[5] = ic * n1 * n2 - s * n0;
  R[6] = ic * n2 * n0 - s * n1; R[7] = ic * n2 * n1 + s * n0;  R[8] = c + ic * n2 * n2;
  float* ro = out_rot + b * 216 + j * 9;
#pragma unroll
  for (int q = 0; q < 9; q++) ro[q] = R[q];
  unsigned short* pf = PF + b * K_;
  if (j > 0) {
#pragma unroll
    for (int q = 0; q < 9; q++)
      pf[10 + (j - 1) * 9 + q] = f2bf(R[q] - ((q % 4 == 0) ? 1.0f : 0.0f));
  } else {
#pragma unroll
    for (int k = 0; k < NB_; k++) pf[k] = f2bf(in[b * 82 + 72 + k]);
#pragma unroll
    for (int k = 217; k < K_; k++) pf[k] = 0;
  }
}

// K_chain: per-batch kinematic chain (round-1-verified version, global staging).
__global__ void __launch_bounds__(64) k_chain(const float* __restrict__ in,
                                              const float* __restrict__ rot,
                                              const float* __restrict__ srtr,
                                              const int* __restrict__ parents,
                                              float* __restrict__ Abuf) {
  __shared__ float Jl[NJ_ * 3 * 64];   // [elem][tid] : bank-conflict free
  int tid = threadIdx.x;
  int b = blockIdx.x * 64 + tid;       // 8 blocks * 64 = 512
  float beta[NB_];
#pragma unroll
  for (int k = 0; k < NB_; k++) beta[k] = in[b * 82 + 72 + k];
#pragma unroll
  for (int j = 0; j < NJ_; j++) {
#pragma unroll
    for (int c = 0; c < 3; c++) {
      float s = srtr[720 + j * 3 + c];
#pragma unroll
      for (int k = 0; k < NB_; k++) s += beta[k] * srtr[(k * NJ_ + j) * 3 + c];
      Jl[(j * 3 + c) * 64 + tid] = s;
    }
  }
  const float* Rb = rot + b * 216;
  float* Ab = Abuf + b * 288;
  // j = 0: world = [R0 | J0]
#pragma unroll
  for (int r = 0; r < 3; r++) {
#pragma unroll
    for (int c = 0; c < 3; c++) Ab[r * 4 + c] = Rb[r * 3 + c];
    Ab[r * 4 + 3] = Jl[(r) * 64 + tid];
  }
  for (int j = 1; j < NJ_; j++) {
    int p = parents[j];
    float t0 = Jl[(j * 3 + 0) * 64 + tid] - Jl[(p * 3 + 0) * 64 + tid];
    float t1 = Jl[(j * 3 + 1) * 64 + tid] - Jl[(p * 3 + 1) * 64 + tid];
    float t2 = Jl[(j * 3 + 2) * 64 + tid] - Jl[(p * 3 + 2) * 64 + tid];
    float Rj[9];
#pragma unroll
    for (int q = 0; q < 9; q++) Rj[q] = Rb[j * 9 + q];
#pragma unroll
    for (int r = 0; r < 3; r++) {
      float p0 = Ab[p * 12 + r * 4 + 0];
      float p1 = Ab[p * 12 + r * 4 + 1];
      float p2 = Ab[p * 12 + r * 4 + 2];
      float p3 = Ab[p * 12 + r * 4 + 3];
#pragma unroll
      for (int c = 0; c < 3; c++)
        Ab[j * 12 + r * 4 + c] = p0 * Rj[c] + p1 * Rj[3 + c] + p2 * Rj[6 + c];
      Ab[j * 12 + r * 4 + 3] = p0 * t0 + p1 * t1 + p2 * t2 + p3;
    }
  }
  // fix pass: t' = tw - Rw @ J  (parents are earlier indices; chain fully done)
#pragma unroll
  for (int j = 0; j < NJ_; j++) {
    float jx = Jl[(j * 3 + 0) * 64 + tid];
    float jy = Jl[(j * 3 + 1) * 64 + tid];
    float jz = Jl[(j * 3 + 2) * 64 + tid];
#pragma unroll
    for (int r = 0; r < 3; r++) {
      float m0 = Ab[j * 12 + r * 4 + 0];
      float m1 = Ab[j * 12 + r * 4 + 1];
      float m2 = Ab[j * 12 + r * 4 + 2];
      Ab[j * 12 + r * 4 + 3] -= (m0 * jx + m1 * jy + m2 * jz);
    }
  }
}

// K_skin: MFMA GEMM (64 b x 192 n tile, B-tile staged in LDS from fp32 sources)
// + fused LBS skinning + joint-regression partials.  Block 256 = 4 waves.
#define BSTRIDE 136   // Btile row stride in shorts: 272 B (16-aligned, 2-way banks)
__global__ void __launch_bounds__(256, 2) k_skin(const unsigned short* __restrict__ PF,
                                                 const float* __restrict__ shapes,
                                                 const float* __restrict__ posedirs,
                                                 const float* __restrict__ vt,
                                                 const float* __restrict__ lbs,
                                                 const float* __restrict__ jreg,
                                                 const float* __restrict__ Abuf,
                                                 float* __restrict__ verts,
                                                 float* __restrict__ jout) {
  // LDS: Btile [192][136] bf16 (52224 B) aliased by Vp [64][193] f32 (49408 B)
  __shared__ __align__(16) char smem[52224 + 6400 + 4864];
  unsigned short* Btile = (unsigned short*)smem;
  float* Vp    = (float*)smem;
  float* lbs_l = (float*)(smem + 52224);          // [64][25]
  float* jr_l  = (float*)(smem + 52224 + 6400);   // [64][19]

  int tid = threadIdx.x;
  int w = tid >> 6, lane = tid & 63;
  int quad = lane >> 4, l15 = lane & 15;
  int v0 = blockIdx.x * 64;            // 108 n-blocks
  int n0 = blockIdx.x * 192;
  int b0 = blockIdx.y * 64;            // 8 b-blocks

  // stage lbs + jreg tiles
  for (int i = tid; i < 64 * NJ_; i += 256) {
    int vl = i / NJ_, jj = i % NJ_;
    int v = v0 + vl;
    lbs_l[vl * 25 + jj] = (v < V_) ? lbs[(size_t)v * NJ_ + jj] : 0.f;
  }
  for (int i = tid; i < 64 * NJO_; i += 256) {
    int vl = i / NJO_, jo = i % NJO_;
    int v = v0 + vl;
    jr_l[i] = (v < V_) ? jreg[(size_t)v * NJO_ + jo] : 0.f;
  }

  f32x4 acc[4][3];
#pragma unroll
  for (int m = 0; m < 4; m++)
#pragma unroll
    for (int ns = 0; ns < 3; ns++) acc[m][ns] = (f32x4){0.f, 0.f, 0.f, 0.f};

  // ---- K phase 0: k in [0,128) ----
  for (int idx = tid; idx < 192 * 128; idx += 256) {
    int i = idx % 192, k = idx / 192;
    float val = 0.f;
    int n = n0 + i;
    if (n < N3V) {
      if (k < NB_) val = shapes[(size_t)k * N3V + n];
      else         val = posedirs[(size_t)(k - 10) * N3V + n];
    }
    Btile[i * BSTRIDE + k] = f2bf(val);
  }
  __syncthreads();
#pragma unroll
  for (int kt = 0; kt < 4; kt++) {
    short8 a[4];
#pragma unroll
    for (int m = 0; m < 4; m++)
      a[m] = *(const short8*)(PF + (size_t)(b0 + m * 16 + l15) * K_ + kt * 32 + quad * 8);
#pragma unroll
    for (int ns = 0; ns < 3; ns++) {
      short8 bfr = *(const short8*)(Btile + (w * 48 + ns * 16 + l15) * BSTRIDE + kt * 32 + quad * 8);
#pragma unroll
      for (int m = 0; m < 4; m++)
        acc[m][ns] = __builtin_amdgcn_mfma_f32_16x16x32_bf16(a[m], bfr, acc[m][ns], 0, 0, 0);
    }
  }
  __syncthreads();
  // ---- K phase 1: k in [128,224) (96 wide; 217..223 zero) ----
  for (int idx = tid; idx < 192 * 96; idx += 256) {
    int i = idx % 192, kk = idx / 192;
    int k = 128 + kk;
    float val = 0.f;
    int n = n0 + i;
    if (n < N3V && k < 217) val = posedirs[(size_t)(k - 10) * N3V + n];
    Btile[i * BSTRIDE + kk] = f2bf(val);
  }
  __syncthreads();
#pragma unroll
  for (int kt = 0; kt < 3; kt++) {
    short8 a[4];
#pragma unroll
    for (int m = 0; m < 4; m++)
      a[m] = *(const short8*)(PF + (size_t)(b0 + m * 16 + l15) * K_ + 128 + kt * 32 + quad * 8);
#pragma unroll
    for (int ns = 0; ns < 3; ns++) {
      short8 bfr = *(const short8*)(Btile + (w * 48 + ns * 16 + l15) * BSTRIDE + kt * 32 + quad * 8);
#pragma unroll
      for (int m = 0; m < 4; m++)
        acc[m][ns] = __builtin_amdgcn_mfma_f32_16x16x32_bf16(a[m], bfr, acc[m][ns], 0, 0, 0);
    }
  }
  __syncthreads();   // all Btile reads done before Vp overwrites (aliased!)

  // C tile -> LDS  (C/D map: col = lane&15, row = quad*4 + reg; m-sub adds m*16)
#pragma unroll
  for (int m = 0; m < 4; m++)
#pragma unroll
    for (int ns = 0; ns < 3; ns++)
#pragma unroll
      for (int reg = 0; reg < 4; reg++)
        Vp[(m * 16 + quad * 4 + reg) * 193 + w * 48 + ns * 16 + l15] = acc[m][ns][reg];
  __syncthreads();

  // ---- skinning: lane = vertex; wave w handles batches bl = w*16 .. w*16+15 ----
  int v = v0 + lane;
  bool vok = v < V_;
  float vtx = 0.f, vty = 0.f, vtz = 0.f;
  if (vok) { vtx = vt[3 * v + 0]; vty = vt[3 * v + 1]; vtz = vt[3 * v + 2]; }
  for (int ib = 0; ib < 16; ib++) {
    int bl = w * 16 + ib;
    int b = __builtin_amdgcn_readfirstlane(b0 + bl);   // wave-uniform -> s_loads for A'
    float x = Vp[bl * 193 + 3 * lane + 0] + vtx;
    float y = Vp[bl * 193 + 3 * lane + 1] + vty;
    float z = Vp[bl * 193 + 3 * lane + 2] + vtz;
    float o0 = 0.f, o1 = 0.f, o2 = 0.f;
    const float* M = Abuf + (size_t)b * 288;
#pragma unroll
    for (int j = 0; j < NJ_; j++) {
      float wg = lbs_l[lane * 25 + j];
      const float* m = M + j * 12;
      o0 += wg * (m[0] * x + m[1] * y + m[2]  * z + m[3]);
      o1 += wg * (m[4] * x + m[5] * y + m[6]  * z + m[7]);
      o2 += wg * (m[8] * x + m[9] * y + m[10] * z + m[11]);
    }
    if (vok) {
      float* op = verts + ((size_t)b * V_ + v) * 3;
      op[0] = o0; op[1] = o1; op[2] = o2;
    }
    Vp[bl * 193 + 3 * lane + 0] = vok ? o0 : 0.f;
    Vp[bl * 193 + 3 * lane + 1] = vok ? o1 : 0.f;
    Vp[bl * 193 + 3 * lane + 2] = vok ? o2 : 0.f;
  }
  __syncthreads();

  // ---- joint partials over this block's 64 vertices ----
  for (int i = tid; i < 64 * NJO_; i += 256) {
    int bl = i / NJO_, jo = i % NJO_;
    float s0 = 0.f, s1 = 0.f, s2 = 0.f;
#pragma unroll 4
    for (int vv = 0; vv < 64; vv++) {
      float wj = jr_l[vv * NJO_ + jo];
      s0 += wj * Vp[bl * 193 + 3 * vv + 0];
      s1 += wj * Vp[bl * 193 + 3 * vv + 1];
      s2 += wj * Vp[bl * 193 + 3 * vv + 2];
    }
    float* jp = jout + (size_t)(b0 + bl) * (NJO_ * 3) + jo * 3;
    atomicAdd(jp + 0, s0);
    atomicAdd(jp + 1, s1);
    atomicAdd(jp + 2, s2);
  }
}

extern "C" void kernel_launch(void* const* d_in, const int* in_sizes, int n_in,
                              void* d_out, int out_size, void* d_ws, size_t ws_size,
                              hipStream_t stream) {
  const float* inputs   = (const float*)d_in[0];
  const float* v_templ  = (const float*)d_in[1];
  const float* shapes   = (const float*)d_in[2];
  const float* posedirs = (const float*)d_in[3];
  const float* sreg     = (const float*)d_in[4];
  const float* lbs      = (const float*)d_in[5];
  const float* jreg     = (const float*)d_in[6];
  const int*   parents  = (const int*)d_in[7];

  float* out   = (float*)d_out;
  float* verts = out;                     // 512*6890*3
  float* jout  = out + 10583040;          // 512*19*3
  float* rot   = out + 10612224;          // 512*24*9

  float* ws = (float*)d_ws;
  unsigned short* PF = (unsigned short*)ws;   // bf16 [512][224] = 57344 floats
  float* Abuf = ws + 57344;                   // fp32 [512][288]
  float* srtr = ws + 204800;                  // 792 floats

  hipMemsetAsync(jout, 0, (size_t)B_ * NJO_ * 3 * sizeof(float), stream);
  k_sr   <<<24, 256, 0, stream>>>(shapes, v_templ, sreg, srtr);
  k_rodpf<<<48, 256, 0, stream>>>(inputs, rot, PF);
  k_chain<<<8, 64, 0, stream>>>(inputs, rot, srtr, parents, Abuf);
  dim3 gskin(108, 8);
  k_skin <<<gskin, 256, 0, stream>>>(PF, shapes, posedirs, v_templ, lbs, jreg, Abuf, verts, jout);
}

// Round 4
// 365.107 us; speedup vs baseline: 1.1667x; 1.1667x over previous
//
#include <hip/hip_runtime.h>
#include <hip/hip_bf16.h>

#define B_   512
#define V_   6890
#define NJ_  24
#define NB_  10
#define NP_  207
#define NJO_ 19
#define K_   224          // 10 beta + 207 pose_feature + 7 zero pad
#define N3V  20670        // V_*3
#define NPAD 20736        // 108 * 192

typedef __attribute__((ext_vector_type(8))) short short8;   // 8 bf16 (4 VGPRs)
typedef __attribute__((ext_vector_type(4))) float f32x4;    // 4 fp32 acc

// -------- ws layout, FAST path (floats), total 2528024 fl = 9.65 MB --------
// PF   : bf16 [512][224]          @ 0        (57344 fl)
// PD   : bf16 [20736][224]        @ 57344    (2322432 fl)
// Abuf : fp32 [512][24*12]        @ 2379776  (147456 fl)
// srtr : SR[10][24][3]+TR[24][3]  @ 2527232  (792 fl)
// -------- ws layout, FALLBACK path (round-1 proven, 1.02 MB) --------
// pf_t : fp32 [207][512] @ 0; Abuf @ 105984; srtr @ 253440

// -------- d_out layout (floats) --------
// vertices @ 0 (10583040) | joints @ 10583040 (29184) | rot @ 10612224 (110592)

__device__ __forceinline__ unsigned short f2bf(float x) {
  __hip_bfloat16 h = __float2bfloat16(x);
  return *(unsigned short*)&h;
}

// ---------------------------------------------------------------- shared: k_sr
__global__ void __launch_bounds__(256) k_sr(const float* __restrict__ shapes,
                                            const float* __restrict__ vt,
                                            const float* __restrict__ sreg,
                                            float* __restrict__ srtr) {
  int j = blockIdx.x;          // 24 blocks
  int tid = threadIdx.x;
  float acc[33];
#pragma unroll
  for (int a = 0; a < 33; a++) acc[a] = 0.f;
  for (int v = tid; v < V_; v += 256) {
    float w = sreg[v * NJ_ + j];
#pragma unroll
    for (int k = 0; k < NB_; k++) {
      const float* sp = shapes + k * N3V + 3 * v;
#pragma unroll
      for (int c = 0; c < 3; c++) acc[k * 3 + c] += w * sp[c];
    }
#pragma unroll
    for (int c = 0; c < 3; c++) acc[30 + c] += w * vt[3 * v + c];
  }
  __shared__ float red[4][33];
  int wave = tid >> 6, lane = tid & 63;
#pragma unroll
  for (int a = 0; a < 33; a++) {
    float x = acc[a];
#pragma unroll
    for (int m = 1; m < 64; m <<= 1) x += __shfl_xor(x, m, 64);
    if (lane == 0) red[wave][a] = x;
  }
  __syncthreads();
  if (tid < 33) {
    float s = red[0][tid] + red[1][tid] + red[2][tid] + red[3][tid];
    if (tid < 30) srtr[((tid / 3) * NJ_ + j) * 3 + (tid % 3)] = s;
    else          srtr[720 + j * 3 + (tid - 30)] = s;
  }
}

// ------------------------------------------------------------- shared: k_chain
__global__ void __launch_bounds__(64) k_chain(const float* __restrict__ in,
                                              const float* __restrict__ rot,
                                              const float* __restrict__ srtr,
                                              const int* __restrict__ parents,
                                              float* __restrict__ Abuf) {
  __shared__ float Jl[NJ_ * 3 * 64];
  int tid = threadIdx.x;
  int b = blockIdx.x * 64 + tid;       // 8 blocks
  float beta[NB_];
#pragma unroll
  for (int k = 0; k < NB_; k++) beta[k] = in[b * 82 + 72 + k];
#pragma unroll
  for (int j = 0; j < NJ_; j++) {
#pragma unroll
    for (int c = 0; c < 3; c++) {
      float s = srtr[720 + j * 3 + c];
#pragma unroll
      for (int k = 0; k < NB_; k++) s += beta[k] * srtr[(k * NJ_ + j) * 3 + c];
      Jl[(j * 3 + c) * 64 + tid] = s;
    }
  }
  const float* Rb = rot + b * 216;
  float* Ab = Abuf + b * 288;
#pragma unroll
  for (int r = 0; r < 3; r++) {
#pragma unroll
    for (int c = 0; c < 3; c++) Ab[r * 4 + c] = Rb[r * 3 + c];
    Ab[r * 4 + 3] = Jl[r * 64 + tid];
  }
  for (int j = 1; j < NJ_; j++) {
    int p = parents[j];
    float t0 = Jl[(j * 3 + 0) * 64 + tid] - Jl[(p * 3 + 0) * 64 + tid];
    float t1 = Jl[(j * 3 + 1) * 64 + tid] - Jl[(p * 3 + 1) * 64 + tid];
    float t2 = Jl[(j * 3 + 2) * 64 + tid] - Jl[(p * 3 + 2) * 64 + tid];
    float Rj[9];
#pragma unroll
    for (int q = 0; q < 9; q++) Rj[q] = Rb[j * 9 + q];
#pragma unroll
    for (int r = 0; r < 3; r++) {
      float p0 = Ab[p * 12 + r * 4 + 0];
      float p1 = Ab[p * 12 + r * 4 + 1];
      float p2 = Ab[p * 12 + r * 4 + 2];
      float p3 = Ab[p * 12 + r * 4 + 3];
#pragma unroll
      for (int c = 0; c < 3; c++)
        Ab[j * 12 + r * 4 + c] = p0 * Rj[c] + p1 * Rj[3 + c] + p2 * Rj[6 + c];
      Ab[j * 12 + r * 4 + 3] = p0 * t0 + p1 * t1 + p2 * t2 + p3;
    }
  }
#pragma unroll
  for (int j = 0; j < NJ_; j++) {
    float jx = Jl[(j * 3 + 0) * 64 + tid];
    float jy = Jl[(j * 3 + 1) * 64 + tid];
    float jz = Jl[(j * 3 + 2) * 64 + tid];
#pragma unroll
    for (int r = 0; r < 3; r++) {
      float m0 = Ab[j * 12 + r * 4 + 0];
      float m1 = Ab[j * 12 + r * 4 + 1];
      float m2 = Ab[j * 12 + r * 4 + 2];
      Ab[j * 12 + r * 4 + 3] -= (m0 * jx + m1 * jy + m2 * jz);
    }
  }
}

// ------------------------------------------------------- FAST path: k_rodpf
__global__ void __launch_bounds__(256) k_rodpf(const float* __restrict__ in,
                                               float* __restrict__ out_rot,
                                               unsigned short* __restrict__ PF) {
  int idx = blockIdx.x * 256 + threadIdx.x;   // 48 blocks
  int b = idx & (B_ - 1);
  int j = idx >> 9;
  const float* r = in + b * 82 + j * 3;
  float r0 = r[0], r1 = r[1], r2 = r[2];
  float ax = r0 + 1e-8f, ay = r1 + 1e-8f, az = r2 + 1e-8f;
  float angle = sqrtf(ax * ax + ay * ay + az * az);
  float inv = 1.0f / angle;
  float n0 = r0 * inv, n1 = r1 * inv, n2 = r2 * inv;
  float c = cosf(angle), s = sinf(angle);
  float ic = 1.0f - c;
  float R[9];
  R[0] = c + ic * n0 * n0;      R[1] = ic * n0 * n1 - s * n2;  R[2] = ic * n0 * n2 + s * n1;
  R[3] = ic * n1 * n0 + s * n2; R[4] = c + ic * n1 * n1;       R[5] = ic * n1 * n2 - s * n0;
  R[6] = ic * n2 * n0 - s * n1; R[7] = ic * n2 * n1 + s * n0;  R[8] = c + ic * n2 * n2;
  float* ro = out_rot + b * 216 + j * 9;
#pragma unroll
  for (int q = 0; q < 9; q++) ro[q] = R[q];
  unsigned short* pf = PF + b * K_;
  if (j > 0) {
#pragma unroll
    for (int q = 0; q < 9; q++)
      pf[10 + (j - 1) * 9 + q] = f2bf(R[q] - ((q % 4 == 0) ? 1.0f : 0.0f));
  } else {
#pragma unroll
    for (int k = 0; k < NB_; k++) pf[k] = f2bf(in[b * 82 + 72 + k]);
#pragma unroll
    for (int k = 217; k < K_; k++) pf[k] = 0;
  }
}

// ------------------------------------------------------- FAST path: k_prep
// PD[n][k] bf16, one uint (k pair) per thread. Reads coalesced along n.
__global__ void __launch_bounds__(256) k_prep(const float* __restrict__ shapes,
                                              const float* __restrict__ posedirs,
                                              unsigned int* __restrict__ PD32) {
  int idx = blockIdx.x * 256 + threadIdx.x;   // 9072 blocks * 256 = 112*NPAD
  int kk = idx / NPAD;                        // 0..111
  int n  = idx - kk * NPAD;
  float v0 = 0.f, v1 = 0.f;
  if (n < N3V) {
    int k0 = 2 * kk, k1 = 2 * kk + 1;
    if (k0 < NB_)       v0 = shapes[(size_t)k0 * N3V + n];
    else if (k0 < 217)  v0 = posedirs[(size_t)(k0 - 10) * N3V + n];
    if (k1 < NB_)       v1 = shapes[(size_t)k1 * N3V + n];
    else if (k1 < 217)  v1 = posedirs[(size_t)(k1 - 10) * N3V + n];
  }
  unsigned int lo = f2bf(v0), hi = f2bf(v1);
  PD32[(size_t)n * 112 + kk] = lo | (hi << 16);
}

// ------------------------------------------------------- FAST path: k_skin
// GEMM straight from global (PF, PD both L2-resident) + fused LBS + joint partials.
#define VPS 197   // Vp row stride (fp32): kills C-write bank conflicts
__global__ void __launch_bounds__(256) k_skin(const unsigned short* __restrict__ PF,
                                              const unsigned short* __restrict__ PD,
                                              const float* __restrict__ vt,
                                              const float* __restrict__ lbs,
                                              const float* __restrict__ jreg,
                                              const float* __restrict__ Abuf,
                                              float* __restrict__ verts,
                                              float* __restrict__ jout) {
  __shared__ float Vp[64 * VPS];        // 50432 B
  __shared__ float lbs_l[64 * 25];      // 6400 B
  __shared__ float jr_l[64 * NJO_];     // 4864 B
  int tid = threadIdx.x;
  int w = tid >> 6, lane = tid & 63;
  int quad = lane >> 4, l15 = lane & 15;
  int v0 = blockIdx.x * 64;             // 108 n-blocks
  int n0 = blockIdx.x * 192;
  int b0 = blockIdx.y * 64;             // 8 b-blocks

  for (int i = tid; i < 64 * NJ_; i += 256) {
    int vl = i / NJ_, jj = i % NJ_;
    int v = v0 + vl;
    lbs_l[vl * 25 + jj] = (v < V_) ? lbs[(size_t)v * NJ_ + jj] : 0.f;
  }
  for (int i = tid; i < 64 * NJO_; i += 256) {
    int vl = i / NJO_, jo = i % NJO_;
    int v = v0 + vl;
    jr_l[i] = (v < V_) ? jreg[(size_t)v * NJO_ + jo] : 0.f;
  }

  f32x4 acc[4][3];
#pragma unroll
  for (int m = 0; m < 4; m++)
#pragma unroll
    for (int ns = 0; ns < 3; ns++) acc[m][ns] = (f32x4){0.f, 0.f, 0.f, 0.f};

#pragma unroll
  for (int kt = 0; kt < 7; kt++) {
    short8 a[4];
#pragma unroll
    for (int m = 0; m < 4; m++)
      a[m] = *(const short8*)(PF + (size_t)(b0 + m * 16 + l15) * K_ + kt * 32 + quad * 8);
#pragma unroll
    for (int ns = 0; ns < 3; ns++) {
      short8 bfr = *(const short8*)(PD + (size_t)(n0 + w * 48 + ns * 16 + l15) * K_ + kt * 32 + quad * 8);
#pragma unroll
      for (int m = 0; m < 4; m++)
        acc[m][ns] = __builtin_amdgcn_mfma_f32_16x16x32_bf16(a[m], bfr, acc[m][ns], 0, 0, 0);
    }
  }

  // C -> LDS  (C/D map: col = lane&15, row = quad*4 + reg)
#pragma unroll
  for (int m = 0; m < 4; m++)
#pragma unroll
    for (int ns = 0; ns < 3; ns++)
#pragma unroll
      for (int reg = 0; reg < 4; reg++)
        Vp[(m * 16 + quad * 4 + reg) * VPS + w * 48 + ns * 16 + l15] = acc[m][ns][reg];
  __syncthreads();

  // skinning: lane = vertex; wave w handles batches w*16 .. w*16+15
  int v = v0 + lane;
  bool vok = v < V_;
  float vtx = 0.f, vty = 0.f, vtz = 0.f;
  if (vok) { vtx = vt[3 * v + 0]; vty = vt[3 * v + 1]; vtz = vt[3 * v + 2]; }
  for (int ib = 0; ib < 16; ib++) {
    int bl = w * 16 + ib;
    int b = __builtin_amdgcn_readfirstlane(b0 + bl);   // wave-uniform -> s_loads
    float x = Vp[bl * VPS + 3 * lane + 0] + vtx;
    float y = Vp[bl * VPS + 3 * lane + 1] + vty;
    float z = Vp[bl * VPS + 3 * lane + 2] + vtz;
    float o0 = 0.f, o1 = 0.f, o2 = 0.f;
    const float* M = Abuf + (size_t)b * 288;
#pragma unroll
    for (int j = 0; j < NJ_; j++) {
      float wg = lbs_l[lane * 25 + j];
      const float* m = M + j * 12;
      o0 += wg * (m[0] * x + m[1] * y + m[2]  * z + m[3]);
      o1 += wg * (m[4] * x + m[5] * y + m[6]  * z + m[7]);
      o2 += wg * (m[8] * x + m[9] * y + m[10] * z + m[11]);
    }
    if (vok) {
      float* op = verts + ((size_t)b * V_ + v) * 3;
      op[0] = o0; op[1] = o1; op[2] = o2;
    }
    Vp[bl * VPS + 3 * lane + 0] = vok ? o0 : 0.f;
    Vp[bl * VPS + 3 * lane + 1] = vok ? o1 : 0.f;
    Vp[bl * VPS + 3 * lane + 2] = vok ? o2 : 0.f;
  }
  __syncthreads();

  for (int i = tid; i < 64 * NJO_; i += 256) {
    int bl = i / NJO_, jo = i % NJO_;
    float s0 = 0.f, s1 = 0.f, s2 = 0.f;
#pragma unroll 4
    for (int vv = 0; vv < 64; vv++) {
      float wj = jr_l[vv * NJO_ + jo];
      s0 += wj * Vp[bl * VPS + 3 * vv + 0];
      s1 += wj * Vp[bl * VPS + 3 * vv + 1];
      s2 += wj * Vp[bl * VPS + 3 * vv + 2];
    }
    float* jp = jout + (size_t)(b0 + bl) * (NJO_ * 3) + jo * 3;
    atomicAdd(jp + 0, s0);
    atomicAdd(jp + 1, s1);
    atomicAdd(jp + 2, s2);
  }
}

// ----------------------------------------------- FALLBACK path (round-1, proven)
__global__ void __launch_bounds__(256) k_rod_fb(const float* __restrict__ in,
                                                float* __restrict__ out_rot,
                                                float* __restrict__ pf_t) {
  int idx = blockIdx.x * 256 + threadIdx.x;
  int b = idx & (B_ - 1);
  int j = idx >> 9;
  const float* r = in + b * 82 + j * 3;
  float r0 = r[0], r1 = r[1], r2 = r[2];
  float ax = r0 + 1e-8f, ay = r1 + 1e-8f, az = r2 + 1e-8f;
  float angle = sqrtf(ax * ax + ay * ay + az * az);
  float inv = 1.0f / angle;
  float n0 = r0 * inv, n1 = r1 * inv, n2 = r2 * inv;
  float c = cosf(angle), s = sinf(angle);
  float ic = 1.0f - c;
  float R[9];
  R[0] = c + ic * n0 * n0;      R[1] = ic * n0 * n1 - s * n2;  R[2] = ic * n0 * n2 + s * n1;
  R[3] = ic * n1 * n0 + s * n2; R[4] = c + ic * n1 * n1;       R[5] = ic * n1 * n2 - s * n0;
  R[6] = ic * n2 * n0 - s * n1; R[7] = ic * n2 * n1 + s * n0;  R[8] = c + ic * n2 * n2;
  float* ro = out_rot + b * 216 + j * 9;
#pragma unroll
  for (int q = 0; q < 9; q++) ro[q] = R[q];
  if (j > 0) {
#pragma unroll
    for (int q = 0; q < 9; q++)
      pf_t[(size_t)((j - 1) * 9 + q) * B_ + b] = R[q] - ((q % 4 == 0) ? 1.0f : 0.0f);
  }
}

#define PB_ 8
__global__ void __launch_bounds__(256) k_main_fb(const float* __restrict__ in,
                                                 const float* __restrict__ shapes,
                                                 const float* __restrict__ vt,
                                                 const float* __restrict__ posedirs,
                                                 const float* __restrict__ lbs,
                                                 const float* __restrict__ pf_t,
                                                 const float* __restrict__ Abuf,
                                                 float* __restrict__ verts) {
  __shared__ float lbs_l[64 * 25];
  int tid = threadIdx.x;
  int v0 = blockIdx.x * 64;
  int b0 = blockIdx.y * 32;
  int nv = V_ - v0; if (nv > 64) nv = 64;
  for (int i = tid; i < nv * NJ_; i += 256)
    lbs_l[(i / NJ_) * 25 + (i % NJ_)] = lbs[(size_t)v0 * NJ_ + i];
  __syncthreads();
  int lane = tid & 63;
  int g = tid >> 6;
  int bb0 = __builtin_amdgcn_readfirstlane(b0 + g * PB_);
  int v = v0 + lane;
  int vc = v < V_ ? v : V_ - 1;
  float acc[PB_][3];
  {
    float t0 = vt[3 * vc + 0], t1 = vt[3 * vc + 1], t2 = vt[3 * vc + 2];
#pragma unroll
    for (int i = 0; i < PB_; i++) { acc[i][0] = t0; acc[i][1] = t1; acc[i][2] = t2; }
  }
#pragma unroll
  for (int k = 0; k < NB_; k++) {
    const float* sp = shapes + k * N3V + 3 * vc;
    float s0 = sp[0], s1 = sp[1], s2 = sp[2];
#pragma unroll
    for (int i = 0; i < PB_; i++) {
      float bv = in[(size_t)(bb0 + i) * 82 + 72 + k];
      acc[i][0] += bv * s0; acc[i][1] += bv * s1; acc[i][2] += bv * s2;
    }
  }
  for (int p = 0; p < NP_; p++) {
    const float* pp = posedirs + (size_t)p * N3V + 3 * vc;
    float d0 = pp[0], d1 = pp[1], d2 = pp[2];
    const float* pfp = pf_t + (size_t)p * B_ + bb0;
#pragma unroll
    for (int i = 0; i < PB_; i++) {
      float f = pfp[i];
      acc[i][0] += f * d0; acc[i][1] += f * d1; acc[i][2] += f * d2;
    }
  }
  float o[PB_][3];
#pragma unroll
  for (int i = 0; i < PB_; i++) { o[i][0] = 0.f; o[i][1] = 0.f; o[i][2] = 0.f; }
  for (int j = 0; j < NJ_; j++) {
    float w = lbs_l[lane * 25 + j];
#pragma unroll
    for (int i = 0; i < PB_; i++) {
      const float* M = Abuf + (size_t)(bb0 + i) * 288 + j * 12;
      float x = acc[i][0], y = acc[i][1], z = acc[i][2];
      o[i][0] += w * (M[0] * x + M[1] * y + M[2]  * z + M[3]);
      o[i][1] += w * (M[4] * x + M[5] * y + M[6]  * z + M[7]);
      o[i][2] += w * (M[8] * x + M[9] * y + M[10] * z + M[11]);
    }
  }
  if (v < V_) {
#pragma unroll
    for (int i = 0; i < PB_; i++) {
      float* op = verts + (size_t)(bb0 + i) * N3V + 3 * v;
      op[0] = o[i][0]; op[1] = o[i][1]; op[2] = o[i][2];
    }
  }
}

__global__ void __launch_bounds__(256) k_joints_fb(const float* __restrict__ verts,
                                                   const float* __restrict__ jreg,
                                                   float* __restrict__ jout) {
  int b = blockIdx.x;
  int tid = threadIdx.x;
  float acc[NJO_ * 3];
#pragma unroll
  for (int a = 0; a < NJO_ * 3; a++) acc[a] = 0.f;
  const float* vb = verts + (size_t)b * N3V;
  for (int v = tid; v < V_; v += 256) {
    float x = vb[3 * v + 0], y = vb[3 * v + 1], z = vb[3 * v + 2];
    const float* jr = jreg + (size_t)v * NJO_;
#pragma unroll
    for (int jo = 0; jo < NJO_; jo++) {
      float w = jr[jo];
      acc[jo * 3 + 0] += w * x; acc[jo * 3 + 1] += w * y; acc[jo * 3 + 2] += w * z;
    }
  }
  __shared__ float red[4][NJO_ * 3];
  int wave = tid >> 6, lane = tid & 63;
#pragma unroll
  for (int a = 0; a < NJO_ * 3; a++) {
    float x = acc[a];
#pragma unroll
    for (int m = 1; m < 64; m <<= 1) x += __shfl_xor(x, m, 64);
    if (lane == 0) red[wave][a] = x;
  }
  __syncthreads();
  if (tid < NJO_ * 3)
    jout[b * (NJO_ * 3) + tid] = red[0][tid] + red[1][tid] + red[2][tid] + red[3][tid];
}

extern "C" void kernel_launch(void* const* d_in, const int* in_sizes, int n_in,
                              void* d_out, int out_size, void* d_ws, size_t ws_size,
                              hipStream_t stream) {
  const float* inputs   = (const float*)d_in[0];
  const float* v_templ  = (const float*)d_in[1];
  const float* shapes   = (const float*)d_in[2];
  const float* posedirs = (const float*)d_in[3];
  const float* sreg     = (const float*)d_in[4];
  const float* lbs      = (const float*)d_in[5];
  const float* jreg     = (const float*)d_in[6];
  const int*   parents  = (const int*)d_in[7];

  float* out   = (float*)d_out;
  float* verts = out;
  float* jout  = out + 10583040;
  float* rot   = out + 10612224;

  float* ws = (float*)d_ws;
  // ws_size is constant across calls -> branch is graph-capture safe.
  bool fast = ws_size >= (size_t)2528024 * 4;

  if (fast) {
    unsigned short* PF = (unsigned short*)ws;          // bf16 [512][224]
    unsigned short* PD = (unsigned short*)(ws + 57344); // bf16 [20736][224]
    float* Abuf = ws + 2379776;
    float* srtr = ws + 2527232;
    hipMemsetAsync(jout, 0, (size_t)B_ * NJO_ * 3 * sizeof(float), stream);
    k_sr   <<<24, 256, 0, stream>>>(shapes, v_templ, sreg, srtr);
    k_rodpf<<<48, 256, 0, stream>>>(inputs, rot, PF);
    k_prep <<<9072, 256, 0, stream>>>(shapes, posedirs, (unsigned int*)PD);
    k_chain<<<8, 64, 0, stream>>>(inputs, rot, srtr, parents, Abuf);
    dim3 gskin(108, 8);
    k_skin <<<gskin, 256, 0, stream>>>(PF, PD, v_templ, lbs, jreg, Abuf, verts, jout);
  } else {
    float* pf_t = ws;                   // fp32 [207][512]
    float* Abuf = ws + 105984;
    float* srtr = ws + 253440;
    k_sr     <<<24, 256, 0, stream>>>(shapes, v_templ, sreg, srtr);
    k_rod_fb <<<48, 256, 0, stream>>>(inputs, rot, pf_t);
    k_chain  <<<8, 64, 0, stream>>>(inputs, rot, srtr, parents, Abuf);
    dim3 gmain(108, 16);
    k_main_fb<<<gmain, 256, 0, stream>>>(inputs, shapes, v_templ, posedirs, lbs, pf_t, Abuf, verts);
    k_joints_fb<<<512, 256, 0, stream>>>(verts, jreg, jout);
  }
}